// Round 2
// baseline (374.068 us; speedup 1.0000x reference)
//
#include <hip/hip_runtime.h>
#include <hip/hip_bf16.h>
#include <stdint.h>

#define N_ATOMS 20000
#define NFEAT   2784
#define KP1     2880      // 45 * 64, K-pad for packed W1
#define SS      500
#define NPAD    20224     // 158 * 128
#define MCOLS   1024      // P*H

typedef __attribute__((ext_vector_type(8))) short s16x8;
typedef __attribute__((ext_vector_type(4))) float f32x4;

static __device__ __forceinline__ unsigned short f2b(float f) {
    __hip_bfloat16 h = __float2bfloat16(f);
    return __builtin_bit_cast(unsigned short, h);
}
static __device__ __forceinline__ float b2f(unsigned short u) {
    unsigned int x = ((unsigned int)u) << 16;
    return __builtin_bit_cast(float, x);
}

#define GLOAD16(g, l) __builtin_amdgcn_global_load_lds( \
    (const __attribute__((address_space(1))) void*)(g), \
    (__attribute__((address_space(3))) void*)(l), 16, 0, 0)

// W fp32 [P][KD][256] -> Bt bf16 [1024][KP];  Bt[p*256+h][k] = W[p][k][h], 0 for k>=KD
__global__ void pack_w(const float* __restrict__ W, unsigned short* __restrict__ Bt,
                       int KD, int KP) {
    __shared__ unsigned short tile[32][256];
    int p = blockIdx.y;
    int f0 = blockIdx.x * 32;
    int t = threadIdx.x;
    #pragma unroll 4
    for (int i = 0; i < 32; ++i) {
        int f = f0 + i;
        float v = (f < KD) ? W[((size_t)p * KD + f) * 256 + t] : 0.f;
        tile[i][t] = f2b(v);
    }
    __syncthreads();
    unsigned short* drow = Bt + (size_t)(p * 256 + t) * KP + f0;
    #pragma unroll
    for (int i = 0; i < 32; i += 4) {
        ushort4 o;
        o.x = tile[i][t]; o.y = tile[i + 1][t]; o.z = tile[i + 2][t]; o.w = tile[i + 3][t];
        *(ushort4*)(drow + i) = o;
    }
}

__global__ void make_pw(const float* __restrict__ Wc, const int* __restrict__ spec,
                        float* __restrict__ pw) {
    int n = blockIdx.x * 256 + threadIdx.x;
    if (n < N_ATOMS) {
        int s = spec[n];
        float4 v = *(const float4*)(Wc + s * 4);
        *(float4*)(pw + n * 4) = v;
    }
}

__global__ void zero_f(float* o, int n) {
    int i = blockIdx.x * 256 + threadIdx.x;
    if (i < n) o[i] = 0.f;
}

// ---------------- Layer-1 FUSED: fp32 features read directly, convert in-kernel --
// 128x128 tile, 8 waves (4M x 2N), BK=64, 44 K-tiles (K=2816 >= 2784, B zeros
// annihilate the clamped-garbage A columns past 2784).
// A path: global fp32 float4 loads -> regs (2-regset ping-pong, issued 1 step
// early) -> bf16 convert -> swizzled ds_write_b128 (T14 issue-early/write-late).
// B path: global_load_lds, linear dest, inverse-swizzled source.
// Double-buffered LDS 64KB -> 2 blocks/CU. Counted waits: vmcnt(2) = A-regs for
// tile t+2 landed; vmcnt(6) = B gloads for tile t+1 landed (queue: Bt+1(2),
// At+3(4), Bt+2(2)). OOB rows/k handled by ADDRESS CLAMP only (finite garbage
// * B-zero = 0; no masking VALU).
__global__ __launch_bounds__(512, 4) void gemm1_fused(
    const float* __restrict__ F,
    const unsigned short* __restrict__ Bt,
    const float* __restrict__ pw,
    unsigned short* __restrict__ C)
{
    __shared__ __align__(16) unsigned short lds_a[2 * 8192];   // 32 KB
    __shared__ __align__(16) unsigned short lds_b[2 * 8192];   // 32 KB

    int bid = blockIdx.x;
    int swz = (bid & 7) * 158 + (bid >> 3);  // bijective XCD chunking (1264 = 8*158)
    int rowTile = swz >> 3;                  // 0..157
    int colTile = swz & 7;                   // 0..7
    int rowBase = rowTile * 128;
    int colBase = colTile * 128;
    int p = colTile >> 1;                    // pseudo-species of this 128-col slab

    int t0 = threadIdx.x;
    int wave = t0 >> 6;
    int lane = t0 & 63;
    int wm = wave >> 1;      // 0..3  (32-row slab)
    int wn = wave & 1;       // 0..1  (64-col slab)

    // ---- A staging geometry: thread covers rows rA, rA+64; logical chunk cl ----
    int rA = t0 >> 3;                 // 0..63
    int cl = t0 & 7;                  // logical 8-elem chunk within the 64-K row
    int cl8 = cl * 8;
    int pc = cl ^ (rA & 7);           // phys chunk (XOR swizzle) for ds_write
    int ar0 = rowBase + rA;      if (ar0 > N_ATOMS - 1) ar0 = N_ATOMS - 1;
    int ar1 = rowBase + rA + 64; if (ar1 > N_ATOMS - 1) ar1 = N_ATOMS - 1;
    const float* fa0 = F + (size_t)ar0 * NFEAT;
    const float* fa1 = F + (size_t)ar1 * NFEAT;
    unsigned short* wA0 = lds_a + rA * 64 + pc * 8;
    unsigned short* wA1 = lds_a + (rA + 64) * 64 + pc * 8;

    // ---- B staging: linear LDS dest, inverse-swizzled global k ----
    int ckl = (cl ^ (rA & 7)) << 3;
    const unsigned short* sb = Bt + (size_t)(colBase + rA) * KP1 + ckl;

    // fragment read bases
    int ra0 = wm * 32 + (lane & 15);
    int rb0 = wn * 64 + (lane & 15);
    int xr = lane & 7;
    int c0 = lane >> 4;

    f32x4 acc[2][4];
    f32x4 z4 = {0.f, 0.f, 0.f, 0.f};
    #pragma unroll
    for (int i = 0; i < 2; ++i)
        #pragma unroll
        for (int j = 0; j < 4; ++j) acc[i][j] = z4;

#define AWRITE(SB, C0, C1, C2, C3) do { \
    s16x8 w0, w1; \
    w0[0] = (short)f2b((C0).x); w0[1] = (short)f2b((C0).y); \
    w0[2] = (short)f2b((C0).z); w0[3] = (short)f2b((C0).w); \
    w0[4] = (short)f2b((C1).x); w0[5] = (short)f2b((C1).y); \
    w0[6] = (short)f2b((C1).z); w0[7] = (short)f2b((C1).w); \
    w1[0] = (short)f2b((C2).x); w1[1] = (short)f2b((C2).y); \
    w1[2] = (short)f2b((C2).z); w1[3] = (short)f2b((C2).w); \
    w1[4] = (short)f2b((C3).x); w1[5] = (short)f2b((C3).y); \
    w1[6] = (short)f2b((C3).z); w1[7] = (short)f2b((C3).w); \
    *(s16x8*)(wA0 + (SB) * 8192) = w0; \
    *(s16x8*)(wA1 + (SB) * 8192) = w1; \
} while (0)

#define BGLOAD(SB) do { \
    GLOAD16(sb, lds_b + (SB) * 8192 + t0 * 8); \
    GLOAD16(sb + (size_t)64 * KP1, lds_b + (SB) * 8192 + 4096 + t0 * 8); \
    sb += 64; \
} while (0)

#define MFMA_ALL \
    _Pragma("unroll") \
    for (int kk = 0; kk < 2; ++kk) \
        _Pragma("unroll") \
        for (int fm = 0; fm < 2; ++fm) \
            _Pragma("unroll") \
            for (int fn = 0; fn < 4; ++fn) \
                acc[fm][fn] = __builtin_amdgcn_mfma_f32_16x16x32_bf16( \
                    af[kk][fm], bv[kk][fn], acc[fm][fn], 0, 0, 0)

#define FRAGS(CB) \
    s16x8 af[2][2], bv[2][4]; \
    _Pragma("unroll") \
    for (int kk = 0; kk < 2; ++kk) { \
        int ch = ((((kk << 2) | c0) ^ xr) << 3); \
        _Pragma("unroll") \
        for (int fm = 0; fm < 2; ++fm) \
            af[kk][fm] = *(const s16x8*)&lds_a[(CB) * 8192 + (ra0 + fm * 16) * 64 + ch]; \
        _Pragma("unroll") \
        for (int fn = 0; fn < 4; ++fn) \
            bv[kk][fn] = *(const s16x8*)&lds_b[(CB) * 8192 + (rb0 + fn * 16) * 64 + ch]; \
    }

    // ---------------- prologue: tiles 0,1 staged; A-regs for tile 2 in flight ---
    float4 a00, a01, a02, a03;   // regset 0
    float4 a10, a11, a12, a13;   // regset 1
    {
        int ko = cl8;            // tile 0
        a00 = *(const float4*)(fa0 + ko);
        a01 = *(const float4*)(fa0 + ko + 4);
        a02 = *(const float4*)(fa1 + ko);
        a03 = *(const float4*)(fa1 + ko + 4);
    }
    __builtin_amdgcn_sched_barrier(0);
    {
        int ko = 64 + cl8;       // tile 1
        a10 = *(const float4*)(fa0 + ko);
        a11 = *(const float4*)(fa0 + ko + 4);
        a12 = *(const float4*)(fa1 + ko);
        a13 = *(const float4*)(fa1 + ko + 4);
    }
    __builtin_amdgcn_sched_barrier(0);
    asm volatile("s_waitcnt vmcnt(4)" ::: "memory");   // tile-0 A regs landed
    AWRITE(0, a00, a01, a02, a03);
    BGLOAD(0);
    asm volatile("s_waitcnt vmcnt(2)" ::: "memory");   // tile-1 A regs landed
    AWRITE(1, a10, a11, a12, a13);
    {
        int ko = 128 + cl8;      // tile 2 -> regset 0
        a00 = *(const float4*)(fa0 + ko);
        a01 = *(const float4*)(fa0 + ko + 4);
        a02 = *(const float4*)(fa1 + ko);
        a03 = *(const float4*)(fa1 + ko + 4);
    }
    __builtin_amdgcn_sched_barrier(0);
    BGLOAD(1);
    asm volatile("s_waitcnt vmcnt(6) lgkmcnt(0)" ::: "memory");  // B0 landed, A-writes drained
    __builtin_amdgcn_s_barrier();
    __builtin_amdgcn_sched_barrier(0);

    int aik = 192;   // k-offset of next A-reg issue (tile 3)

// Full step computing tile t (CB=t&1). Consumes regset C* (A data tile t+2),
// fills regset L* (tile t+3) when DO_AI. WN: counted wait after MFMA.
#define FSTEP(CB, C0, C1, C2, C3, L0, L1, L2, L3, DO_AI, WN) do { \
    FRAGS(CB); \
    asm volatile("s_waitcnt lgkmcnt(0)" ::: "memory"); \
    __builtin_amdgcn_sched_barrier(0); \
    __builtin_amdgcn_s_barrier();            /* all waves done reading CB */ \
    __builtin_amdgcn_sched_barrier(0); \
    asm volatile("s_waitcnt vmcnt(2)" ::: "memory");  /* A regs (tile t+2) landed */ \
    __builtin_amdgcn_sched_barrier(0); \
    AWRITE(CB, C0, C1, C2, C3); \
    if (DO_AI) { \
        int ko = aik + cl8; if (ko > NFEAT - 8) ko = NFEAT - 8; \
        L0 = *(const float4*)(fa0 + ko); \
        L1 = *(const float4*)(fa0 + ko + 4); \
        L2 = *(const float4*)(fa1 + ko); \
        L3 = *(const float4*)(fa1 + ko + 4); \
        aik += 64; \
    } \
    __builtin_amdgcn_sched_barrier(0); \
    BGLOAD(CB); \
    __builtin_amdgcn_s_setprio(1); \
    MFMA_ALL; \
    __builtin_amdgcn_s_setprio(0); \
    asm volatile("s_waitcnt vmcnt(" #WN ") lgkmcnt(0)" ::: "memory"); /* B(t+1) landed */ \
    __builtin_amdgcn_s_barrier(); \
    __builtin_amdgcn_sched_barrier(0); \
} while (0)

// Tail step: no staging. DRAIN waits last B loads before final tile's reads.
#define TSTEP(CB, DRAIN) do { \
    FRAGS(CB); \
    asm volatile("s_waitcnt lgkmcnt(0)" ::: "memory"); \
    __builtin_amdgcn_sched_barrier(0); \
    __builtin_amdgcn_s_setprio(1); \
    MFMA_ALL; \
    __builtin_amdgcn_s_setprio(0); \
    if (DRAIN) { \
        asm volatile("s_waitcnt vmcnt(0)" ::: "memory"); \
        __builtin_amdgcn_s_barrier(); \
        __builtin_amdgcn_sched_barrier(0); \
    } \
} while (0)

    // 44 tiles (t=0..43): 41 full steps (t=0..40), NOAI (t=41), then 2 tails
    for (int it = 0; it < 20; ++it) {
        FSTEP(0, a00, a01, a02, a03, a10, a11, a12, a13, 1, 6);
        FSTEP(1, a10, a11, a12, a13, a00, a01, a02, a03, 1, 6);
    }
    FSTEP(0, a00, a01, a02, a03, a10, a11, a12, a13, 1, 6);  // t=40, issues A(43)
    FSTEP(1, a10, a11, a12, a13, a00, a01, a02, a03, 0, 2);  // t=41, stages tile 43
    TSTEP(0, 1);     // t=42, then drain B(43)
    TSTEP(1, 0);     // t=43
#undef FSTEP
#undef TSTEP
#undef FRAGS
#undef MFMA_ALL
#undef BGLOAD
#undef AWRITE

    // epilogue: C/D map col=lane&15, row=(lane>>4)*4+j  [m89-verified]
    int rGrp = (lane >> 4) << 2;
    int cLane = lane & 15;
    #pragma unroll
    for (int fm = 0; fm < 2; ++fm) {
        int r0 = rowBase + wm * 32 + fm * 16 + rGrp;
        float pwv[4];
        #pragma unroll
        for (int j = 0; j < 4; ++j) pwv[j] = pw[(size_t)(r0 + j) * 4 + p];
        #pragma unroll
        for (int fn = 0; fn < 4; ++fn) {
            int c = colBase + wn * 64 + fn * 16 + cLane;
            f32x4 a = acc[fm][fn];
            #pragma unroll
            for (int j = 0; j < 4; ++j) {
                float x = a[j] * pwv[j];
                float s = x / (1.f + __expf(-x));
                C[(size_t)(r0 + j) * MCOLS + c] = f2b(s);
            }
        }
    }
}

// ---------------- Layers 2/3: 128x128 tile, 2x2 waves, BK=64 (block-diag) -------
template<int USE_PW>
__global__ __launch_bounds__(256, 2) void gemm_silu(
    const unsigned short* __restrict__ A, int lda,
    const unsigned short* __restrict__ Bt, int ldb,
    int K, int aOffPerP,
    const float* __restrict__ pw,
    unsigned short* __restrict__ C)
{
    __shared__ __align__(16) unsigned short lds_a[128 * 64];
    __shared__ __align__(16) unsigned short lds_b[128 * 64];

    int bid = blockIdx.x;
    int colTile = bid & 7;
    int rowTile = bid >> 3;
    int rowBase = rowTile * 128;
    int colBase = colTile * 128;
    int p = colBase >> 8;
    int aOff = p * aOffPerP;

    int t = threadIdx.x;
    int wave = t >> 6;
    int lane = t & 63;
    int wm = wave >> 1, wn = wave & 1;

    int trow = t >> 3;
    int kcol = (((t & 7) ^ (trow & 7)) << 3);
    const unsigned short* srcA = A + (size_t)(rowBase + trow) * lda + aOff + kcol;
    const unsigned short* srcB = Bt + (size_t)(colBase + trow) * ldb + kcol;

    f32x4 acc[4][4];
    f32x4 z4 = {0.f, 0.f, 0.f, 0.f};
    #pragma unroll
    for (int i = 0; i < 4; ++i)
        #pragma unroll
        for (int j = 0; j < 4; ++j) acc[i][j] = z4;

    int rb = wm * 64 + (lane & 15);
    int cb = wn * 64 + (lane & 15);
    int c0 = lane >> 4;
    int xr = lane & 7;

    int KT = K >> 6;
    for (int kt = 0; kt < KT; ++kt) {
        #pragma unroll
        for (int i = 0; i < 4; ++i) {
            GLOAD16(srcA + (size_t)i * 32 * lda, lds_a + i * 2048 + wave * 512);
            GLOAD16(srcB + (size_t)i * 32 * ldb, lds_b + i * 2048 + wave * 512);
        }
        srcA += 64; srcB += 64;
        __syncthreads();

        #pragma unroll
        for (int kk = 0; kk < 2; ++kk) {
            s16x8 af[4], bfr[4];
            int ch = (((kk << 2) | c0) ^ xr) << 3;
            #pragma unroll
            for (int fm = 0; fm < 4; ++fm)
                af[fm] = *(const s16x8*)&lds_a[(rb + fm * 16) * 64 + ch];
            #pragma unroll
            for (int fn = 0; fn < 4; ++fn)
                bfr[fn] = *(const s16x8*)&lds_b[(cb + fn * 16) * 64 + ch];
            #pragma unroll
            for (int fm = 0; fm < 4; ++fm)
                #pragma unroll
                for (int fn = 0; fn < 4; ++fn)
                    acc[fm][fn] = __builtin_amdgcn_mfma_f32_16x16x32_bf16(
                        af[fm], bfr[fn], acc[fm][fn], 0, 0, 0);
        }
        __syncthreads();
    }

    int rGrp = (lane >> 4) << 2;
    int cLane = lane & 15;
    #pragma unroll
    for (int fm = 0; fm < 4; ++fm) {
        int r0 = rowBase + wm * 64 + fm * 16 + rGrp;
        float pwv[4];
        if (USE_PW) {
            #pragma unroll
            for (int j = 0; j < 4; ++j) pwv[j] = pw[(size_t)(r0 + j) * 4 + p];
        }
        #pragma unroll
        for (int fn = 0; fn < 4; ++fn) {
            int c = colBase + wn * 64 + fn * 16 + cLane;
            f32x4 a = acc[fm][fn];
            #pragma unroll
            for (int j = 0; j < 4; ++j) {
                float x = a[j];
                if (USE_PW) x *= pwv[j];
                float s = x / (1.f + __expf(-x));
                C[(size_t)(r0 + j) * MCOLS + c] = f2b(s);
            }
        }
    }
}

// e[n] = sum_{p,h} h3[n, p*256+h] * W4flat[p*256+h] * 0.5; atomicAdd(out[sidx[n]], e/40)
__global__ void finalize(const unsigned short* __restrict__ h3,
                         const float* __restrict__ W4,
                         const int* __restrict__ sidx,
                         float* __restrict__ out) {
    int atom = blockIdx.x * 4 + (threadIdx.x >> 6);
    int lane = threadIdx.x & 63;
    if (atom >= N_ATOMS) return;
    const uint32_t* hu = (const uint32_t*)(h3 + (size_t)atom * MCOLS) + lane * 8;
    const float* w = W4 + lane * 16;
    float sum = 0.f;
    #pragma unroll
    for (int i = 0; i < 8; ++i) {
        uint32_t u = hu[i];
        sum += b2f((unsigned short)(u & 0xffff)) * w[2 * i];
        sum += b2f((unsigned short)(u >> 16)) * w[2 * i + 1];
    }
    #pragma unroll
    for (int off = 32; off > 0; off >>= 1) sum += __shfl_down(sum, off);
    if (lane == 0) atomicAdd(out + sidx[atom], sum * 0.0125f);  // (1/sqrt(4))/40
}

extern "C" void kernel_launch(void* const* d_in, const int* in_sizes, int n_in,
                              void* d_out, int out_size, void* d_ws, size_t ws_size,
                              hipStream_t stream) {
    const float* features = (const float*)d_in[0];
    const float* W_comb   = (const float*)d_in[1];
    const float* W1       = (const float*)d_in[2];
    const float* W2       = (const float*)d_in[3];
    const float* W3       = (const float*)d_in[4];
    const float* W4       = (const float*)d_in[5];
    const int*   species  = (const int*)d_in[6];
    const int*   sidx     = (const int*)d_in[7];
    float* out = (float*)d_out;

    char* ws = (char*)d_ws;
    size_t off = 0;
    auto carve = [&](size_t bytes) {
        char* r = ws + off;
        off += (bytes + 255) & ~(size_t)255;
        return r;
    };
    unsigned short* B1t  = (unsigned short*)carve((size_t)1024 * KP1 * 2 + 4096); // 5.9 MB
    unsigned short* B2t  = (unsigned short*)carve((size_t)1024 * 256 * 2);
    unsigned short* B3t  = (unsigned short*)carve((size_t)1024 * 256 * 2);
    float*          pw   = (float*)carve((size_t)NPAD * 4 * 4);
    unsigned short* h1   = (unsigned short*)carve((size_t)NPAD * 1024 * 2);  // 41.4 MB
    unsigned short* h2   = (unsigned short*)carve((size_t)NPAD * 1024 * 2);  // 41.4 MB
    carve(4096);                                                             // slack

    pack_w<<<dim3(KP1 / 32, 4), 256, 0, stream>>>(W1, B1t, NFEAT, KP1);
    pack_w<<<dim3(8, 4), 256, 0, stream>>>(W2, B2t, 256, 256);
    pack_w<<<dim3(8, 4), 256, 0, stream>>>(W3, B3t, 256, 256);
    make_pw<<<(N_ATOMS + 255) / 256, 256, 0, stream>>>(W_comb, species, pw);
    zero_f<<<2, 256, 0, stream>>>(out, SS);

    // layer 1 (fused fp32->bf16): [NPAD x 2784] * [2784 x 1024] -> h1
    gemm1_fused<<<158 * 8, 512, 0, stream>>>(features, B1t, pw, h1);
    // layer 2: block-diagonal, A col offset p*256
    gemm_silu<0><<<158 * 8, 256, 0, stream>>>(h1, 1024, B2t, 256, 256, 256, nullptr, h2);
    // layer 3
    gemm_silu<0><<<158 * 8, 256, 0, stream>>>(h2, 1024, B3t, 256, 256, 256, nullptr, h1);
    // layer 4 + segment sum
    finalize<<<N_ATOMS / 4, 256, 0, stream>>>(h1, W4, sidx, out);
}

// Round 3
// 328.183 us; speedup vs baseline: 1.1398x; 1.1398x over previous
//
#include <hip/hip_runtime.h>
#include <hip/hip_bf16.h>
#include <stdint.h>

#define N_ATOMS 20000
#define NFEAT   2784
#define KP1     2880      // 45 * 64, K-pad for layer 1
#define KT1     45        // K tiles of 64
#define SS      500
#define NPAD    20224     // 158 * 128 = 316 * 64
#define MCOLS   1024      // P*H

typedef __attribute__((ext_vector_type(8))) short s16x8;
typedef __attribute__((ext_vector_type(4))) float f32x4;

static __device__ __forceinline__ unsigned short f2b(float f) {
    __hip_bfloat16 h = __float2bfloat16(f);
    return __builtin_bit_cast(unsigned short, h);
}
static __device__ __forceinline__ float b2f(unsigned short u) {
    unsigned int x = ((unsigned int)u) << 16;
    return __builtin_bit_cast(float, x);
}

#define GLOAD16(g, l) __builtin_amdgcn_global_load_lds( \
    (const __attribute__((address_space(1))) void*)(g), \
    (__attribute__((address_space(3))) void*)(l), 16, 0, 0)

// features fp32 [N, 2784] -> bf16 [NPAD, 2880] (K-pad zeros; pad rows untouched)
__global__ void conv_feat(const float* __restrict__ F, unsigned short* __restrict__ out) {
    int row = blockIdx.x;
    int t = threadIdx.x;
    const float4* src = (const float4*)(F + (size_t)row * NFEAT);
    unsigned short* dst = out + (size_t)row * KP1;
    for (int g = t; g < KP1 / 4; g += 256) {
        float4 v;
        if (g < NFEAT / 4) v = src[g];
        else { v.x = 0.f; v.y = 0.f; v.z = 0.f; v.w = 0.f; }
        ushort4 o;
        o.x = f2b(v.x); o.y = f2b(v.y); o.z = f2b(v.z); o.w = f2b(v.w);
        *(ushort4*)(dst + g * 4) = o;
    }
}

// W fp32 [P][KD][256] -> Bt bf16 [1024][KP];  Bt[p*256+h][k] = W[p][k][h], 0 for k>=KD
__global__ void pack_w(const float* __restrict__ W, unsigned short* __restrict__ Bt,
                       int KD, int KP) {
    __shared__ unsigned short tile[32][256];
    int p = blockIdx.y;
    int f0 = blockIdx.x * 32;
    int t = threadIdx.x;
    #pragma unroll 4
    for (int i = 0; i < 32; ++i) {
        int f = f0 + i;
        float v = (f < KD) ? W[((size_t)p * KD + f) * 256 + t] : 0.f;
        tile[i][t] = f2b(v);
    }
    __syncthreads();
    unsigned short* drow = Bt + (size_t)(p * 256 + t) * KP + f0;
    #pragma unroll
    for (int i = 0; i < 32; i += 4) {
        ushort4 o;
        o.x = tile[i][t]; o.y = tile[i + 1][t]; o.z = tile[i + 2][t]; o.w = tile[i + 3][t];
        *(ushort4*)(drow + i) = o;
    }
}

__global__ void make_pw(const float* __restrict__ Wc, const int* __restrict__ spec,
                        float* __restrict__ pw) {
    int n = blockIdx.x * 256 + threadIdx.x;
    if (n < N_ATOMS) {
        int s = spec[n];
        float4 v = *(const float4*)(Wc + s * 4);
        *(float4*)(pw + n * 4) = v;
    }
}

__global__ void zero_f(float* o, int n) {
    int i = blockIdx.x * 256 + threadIdx.x;
    if (i < n) o[i] = 0.f;
}

// ---------------- Layer-1: 128x128 tile, 8 waves (4M x 2N), BK=64 ----------------
// Double-buffered LDS (A 2x16KB + B 2x16KB = 64KB) -> 2 blocks/CU, 16 waves/CU:
// cross-block overlap hides barrier drain. 2-deep prefetch, counted vmcnt(4),
// raw s_barrier. LDS rows are 128B = 8 chunks of 16B, chunk XOR-swizzled with
// (row&7): linear LDS dest (global_load_lds), inverse-swizzled global source,
// swizzled read.  [R1-proven: 148 us, MfmaUtil 34]
__global__ __launch_bounds__(512, 4) void gemm1_pipe(
    const unsigned short* __restrict__ A,
    const unsigned short* __restrict__ Bt,
    const float* __restrict__ pw,
    unsigned short* __restrict__ C)
{
    __shared__ __align__(16) unsigned short lds_a[2 * 8192];   // 32 KB
    __shared__ __align__(16) unsigned short lds_b[2 * 8192];   // 32 KB

    int bid = blockIdx.x;
    int swz = (bid & 7) * 158 + (bid >> 3);  // bijective XCD chunking (1264 = 8*158)
    int rowTile = swz >> 3;                  // 0..157
    int colTile = swz & 7;                   // 0..7
    int rowBase = rowTile * 128;
    int colBase = colTile * 128;
    int p = colTile >> 1;                    // pseudo-species of this 128-col slab

    int t0 = threadIdx.x;
    int wave = t0 >> 6;
    int lane = t0 & 63;
    int wm = wave >> 1;      // 0..3  (32-row slab)
    int wn = wave & 1;       // 0..1  (64-col slab)

    // staging addresses: thread t0 covers LDS row (i*64 + t0/8), phys chunk (t0&7)
    int rA = t0 >> 3;                         // 0..63
    int ckl = ((t0 & 7) ^ (rA & 7)) << 3;     // inverse-swizzled k elem offset
    const unsigned short* sa = A + (size_t)(rowBase + rA) * KP1 + ckl;
    const unsigned short* sb = Bt + (size_t)(colBase + rA) * KP1 + ckl;

    // fragment read bases
    int ra0 = wm * 32 + (lane & 15);
    int rb0 = wn * 64 + (lane & 15);
    int xr = lane & 7;
    int c0 = lane >> 4;

    f32x4 acc[2][4];
    f32x4 z4 = {0.f, 0.f, 0.f, 0.f};
    #pragma unroll
    for (int i = 0; i < 2; ++i)
        #pragma unroll
        for (int j = 0; j < 4; ++j) acc[i][j] = z4;

#define STAGE1(SB) do { \
    GLOAD16(sa,                     lds_a + (SB) * 8192 + t0 * 8); \
    GLOAD16(sa + (size_t)64 * KP1,  lds_a + (SB) * 8192 + 4096 + t0 * 8); \
    GLOAD16(sb,                     lds_b + (SB) * 8192 + t0 * 8); \
    GLOAD16(sb + (size_t)64 * KP1,  lds_b + (SB) * 8192 + 4096 + t0 * 8); \
    sa += 64; sb += 64; \
} while (0)

    // prologue: stage tiles 0 and 1
    STAGE1(0);
    STAGE1(1);
    asm volatile("s_waitcnt vmcnt(4)" ::: "memory");   // tile 0 landed
    __builtin_amdgcn_s_barrier();
    __builtin_amdgcn_sched_barrier(0);

// Full step on buffer CB (holds tile t, landed): read frags, read-done barrier,
// overwrite CB with tile t+2, MFMA, wait for tile t+1 (in CB^1), barrier.
#define FSTEP(CB) do { \
    s16x8 af[2][2], bv[2][4]; \
    _Pragma("unroll") \
    for (int kk = 0; kk < 2; ++kk) { \
        int ch = ((((kk << 2) | c0) ^ xr) << 3); \
        _Pragma("unroll") \
        for (int fm = 0; fm < 2; ++fm) \
            af[kk][fm] = *(const s16x8*)&lds_a[(CB) * 8192 + (ra0 + fm * 16) * 64 + ch]; \
        _Pragma("unroll") \
        for (int fn = 0; fn < 4; ++fn) \
            bv[kk][fn] = *(const s16x8*)&lds_b[(CB) * 8192 + (rb0 + fn * 16) * 64 + ch]; \
    } \
    asm volatile("s_waitcnt lgkmcnt(0)" ::: "memory"); \
    __builtin_amdgcn_sched_barrier(0); \
    __builtin_amdgcn_s_barrier();            /* all waves done reading CB */ \
    __builtin_amdgcn_sched_barrier(0); \
    STAGE1(CB);                              /* tile t+2 over CB */ \
    __builtin_amdgcn_s_setprio(1); \
    _Pragma("unroll") \
    for (int kk = 0; kk < 2; ++kk) \
        _Pragma("unroll") \
        for (int fm = 0; fm < 2; ++fm) \
            _Pragma("unroll") \
            for (int fn = 0; fn < 4; ++fn) \
                acc[fm][fn] = __builtin_amdgcn_mfma_f32_16x16x32_bf16( \
                    af[kk][fm], bv[kk][fn], acc[fm][fn], 0, 0, 0); \
    __builtin_amdgcn_s_setprio(0); \
    asm volatile("s_waitcnt vmcnt(4)" ::: "memory");   /* tile t+1 landed */ \
    __builtin_amdgcn_s_barrier(); \
    __builtin_amdgcn_sched_barrier(0); \
} while (0)

// Tail step: no staging. DRAIN=1 waits remaining loads + barrier (before last tile).
#define TSTEP(CB, DRAIN) do { \
    s16x8 af[2][2], bv[2][4]; \
    _Pragma("unroll") \
    for (int kk = 0; kk < 2; ++kk) { \
        int ch = ((((kk << 2) | c0) ^ xr) << 3); \
        _Pragma("unroll") \
        for (int fm = 0; fm < 2; ++fm) \
            af[kk][fm] = *(const s16x8*)&lds_a[(CB) * 8192 + (ra0 + fm * 16) * 64 + ch]; \
        _Pragma("unroll") \
        for (int fn = 0; fn < 4; ++fn) \
            bv[kk][fn] = *(const s16x8*)&lds_b[(CB) * 8192 + (rb0 + fn * 16) * 64 + ch]; \
    } \
    _Pragma("unroll") \
    for (int kk = 0; kk < 2; ++kk) \
        _Pragma("unroll") \
        for (int fm = 0; fm < 2; ++fm) \
            _Pragma("unroll") \
            for (int fn = 0; fn < 4; ++fn) \
                acc[fm][fn] = __builtin_amdgcn_mfma_f32_16x16x32_bf16( \
                    af[kk][fm], bv[kk][fn], acc[fm][fn], 0, 0, 0); \
    if (DRAIN) { \
        asm volatile("s_waitcnt vmcnt(0)" ::: "memory"); \
        __builtin_amdgcn_s_barrier(); \
        __builtin_amdgcn_sched_barrier(0); \
    } \
} while (0)

    // 45 tiles: 43 full steps (stage tiles 2..44) = 21 pairs + 1, then 2 tail steps
    for (int it = 0; it < 21; ++it) {
        FSTEP(0);
        FSTEP(1);
    }
    FSTEP(0);        // t=42, stages tile 44 into buf0
    TSTEP(1, 1);     // t=43 (tile 43 in buf1), then drain tile 44
    TSTEP(0, 0);     // t=44 (tile 44 in buf0)
#undef FSTEP
#undef TSTEP
#undef STAGE1

    // epilogue: C/D map col=lane&15, row=(lane>>4)*4+j  [m89-verified]
    int rGrp = (lane >> 4) << 2;
    int cLane = lane & 15;
    #pragma unroll
    for (int fm = 0; fm < 2; ++fm) {
        int r0 = rowBase + wm * 32 + fm * 16 + rGrp;
        float pwv[4];
        #pragma unroll
        for (int j = 0; j < 4; ++j) pwv[j] = pw[(size_t)(r0 + j) * 4 + p];
        #pragma unroll
        for (int fn = 0; fn < 4; ++fn) {
            int c = colBase + wn * 64 + fn * 16 + cLane;
            f32x4 a = acc[fm][fn];
            #pragma unroll
            for (int j = 0; j < 4; ++j) {
                float x = a[j] * pwv[j];
                float s = x / (1.f + __expf(-x));
                C[(size_t)(r0 + j) * MCOLS + c] = f2b(s);
            }
        }
    }
}

// ---------------- Fused tail: layers 2 + 3 + 4 + segment-sum -------------------
// Block = 64 atom rows x one p-slab (grid 316*4). Both layer GEMMs are
// block-diagonal per-p with K=256, so the whole chain is block-local:
//   stage h1[r0:r0+64][p*256:+256] -> LDS (swizzled, via pre-swizzled-global
//   global_load_lds) -> GEMM vs W2t[p] (B-frags straight from global; W2t[p]
//   is 128KB re-read by 316 blocks -> L2-resident) -> silu -> LDS -> GEMM vs
//   W3t[p] -> silu -> LDS -> dot W4[p] -> one atomicAdd per atom.
// Kills h2/h3 HBM round-trips (164 MB) + 2 kernel launches.
// LDS 64KB -> 2 blocks/CU. 4 waves; wave w owns col-slab w*64 (acc 4x4 frags).
__global__ __launch_bounds__(256, 2) void mlp_tail(
    const unsigned short* __restrict__ h1,
    const unsigned short* __restrict__ B2t,
    const unsigned short* __restrict__ B3t,
    const float* __restrict__ W4,
    const int* __restrict__ sidx,
    float* __restrict__ out)
{
    __shared__ __align__(16) unsigned short bufA[64 * 256];  // 32 KB
    __shared__ __align__(16) unsigned short bufH[64 * 256];  // 32 KB

    int bid = blockIdx.x;
    int p  = bid & 3;
    int rg = bid >> 2;
    int r0 = rg * 64;

    int t = threadIdx.x;
    int wave = t >> 6;       // 0..3: col-slab
    int lane = t & 63;
    int rl = lane & 15;
    int hi = lane >> 4;      // 0..3
    int rGrp = hi << 2;

    // ---- stage h1 slab into bufA (swizzled layout) ----
    // LDS phys chunk pc (16B) of row holds logical chunk lc = (pc&24)|((pc&7)^(row&7)).
    // global_load_lds: linear LDS dest, per-lane pre-swizzled global source.
    {
        int pcs = t & 31;
        #pragma unroll
        for (int i = 0; i < 8; ++i) {
            int row_s = i * 8 + (t >> 5);
            int lcs = (pcs & 24) | ((pcs & 7) ^ (row_s & 7));
            const unsigned short* g =
                h1 + ((size_t)(r0 + row_s) * MCOLS + p * 256 + lcs * 8);
            GLOAD16(g, bufA + i * 2048 + t * 8);
        }
    }
    __syncthreads();

    f32x4 acc[4][4];
    f32x4 z4 = {0.f, 0.f, 0.f, 0.f};

// One fused layer: DST = silu(SRC @ BT[p]) entirely in LDS.
// B-frags from global (L2-hot): Bt row = out-col, 256 k contiguous.
#define LAYER(SRC, BT, DST) do { \
    _Pragma("unroll") \
    for (int i = 0; i < 4; ++i) \
        _Pragma("unroll") \
        for (int j = 0; j < 4; ++j) acc[i][j] = z4; \
    const unsigned short* bp = (BT) + ((size_t)(p * 256 + wave * 64 + rl) * 256); \
    _Pragma("unroll") \
    for (int ks = 0; ks < 8; ++ks) { \
        s16x8 af[4], bv[4]; \
        _Pragma("unroll") \
        for (int fn = 0; fn < 4; ++fn) \
            bv[fn] = *(const s16x8*)(bp + (size_t)fn * 16 * 256 + ks * 32 + hi * 8); \
        _Pragma("unroll") \
        for (int fm = 0; fm < 4; ++fm) { \
            int row = fm * 16 + rl; \
            int lc = ks * 4 + hi; \
            int pc = (lc & 24) | ((lc & 7) ^ (row & 7)); \
            af[fm] = *(const s16x8*)&(SRC)[row * 256 + pc * 8]; \
        } \
        _Pragma("unroll") \
        for (int fm = 0; fm < 4; ++fm) \
            _Pragma("unroll") \
            for (int fn = 0; fn < 4; ++fn) \
                acc[fm][fn] = __builtin_amdgcn_mfma_f32_16x16x32_bf16( \
                    af[fm], bv[fn], acc[fm][fn], 0, 0, 0); \
    } \
    /* silu + write to DST (swizzled). No pre-write barrier needed: DST's   */ \
    /* previous readers all finished before the barrier that preceded this  */ \
    /* layer's reads of SRC.                                                */ \
    _Pragma("unroll") \
    for (int fm = 0; fm < 4; ++fm) \
        _Pragma("unroll") \
        for (int fn = 0; fn < 4; ++fn) { \
            _Pragma("unroll") \
            for (int j = 0; j < 4; ++j) { \
                int row = fm * 16 + rGrp + j; \
                int col = wave * 64 + fn * 16 + rl; \
                float x = acc[fm][fn][j]; \
                float s = x / (1.f + __expf(-x)); \
                int lc = col >> 3; \
                int pc = (lc & 24) | ((lc & 7) ^ (row & 7)); \
                (DST)[row * 256 + pc * 8 + (col & 7)] = f2b(s); \
            } \
        } \
    __syncthreads(); \
} while (0)

    LAYER(bufA, B2t, bufH);   // layer 2: h2 = silu(h1p @ W2[p])
    LAYER(bufH, B3t, bufA);   // layer 3: h3 = silu(h2 @ W3[p])
#undef LAYER

    // ---- layer 4: e = h3 . W4[p]; reduce over 4 lanes/row; atomicAdd ----
    {
        int row = t >> 2;        // 0..63
        int q = t & 3;           // covers logical chunks q*8 .. q*8+7
        const float* w4 = W4 + p * 256;
        float sum = 0.f;
        #pragma unroll
        for (int c = 0; c < 8; ++c) {
            int lc = q * 8 + c;
            int pc = (lc & 24) | ((lc & 7) ^ (row & 7));
            s16x8 v = *(const s16x8*)&bufA[row * 256 + pc * 8];
            #pragma unroll
            for (int e = 0; e < 8; ++e)
                sum += b2f((unsigned short)v[e]) * w4[lc * 8 + e];
        }
        sum += __shfl_down(sum, 2);
        sum += __shfl_down(sum, 1);
        int atom = r0 + row;
        if (q == 0 && atom < N_ATOMS)
            atomicAdd(out + sidx[atom], sum * 0.0125f);  // (1/sqrt(4))/40
    }
}

extern "C" void kernel_launch(void* const* d_in, const int* in_sizes, int n_in,
                              void* d_out, int out_size, void* d_ws, size_t ws_size,
                              hipStream_t stream) {
    const float* features = (const float*)d_in[0];
    const float* W_comb   = (const float*)d_in[1];
    const float* W1       = (const float*)d_in[2];
    const float* W2       = (const float*)d_in[3];
    const float* W3       = (const float*)d_in[4];
    const float* W4       = (const float*)d_in[5];
    const int*   species  = (const int*)d_in[6];
    const int*   sidx     = (const int*)d_in[7];
    float* out = (float*)d_out;

    char* ws = (char*)d_ws;
    size_t off = 0;
    auto carve = [&](size_t bytes) {
        char* r = ws + off;
        off += (bytes + 255) & ~(size_t)255;
        return r;
    };
    unsigned short* feat = (unsigned short*)carve((size_t)NPAD * KP1 * 2);   // 116.5 MB
    unsigned short* B1t  = (unsigned short*)carve((size_t)1024 * KP1 * 2 + 4096); // 5.9 MB
    unsigned short* B2t  = (unsigned short*)carve((size_t)1024 * 256 * 2);
    unsigned short* B3t  = (unsigned short*)carve((size_t)1024 * 256 * 2);
    float*          pw   = (float*)carve((size_t)NPAD * 4 * 4);
    unsigned short* h1   = (unsigned short*)carve((size_t)NPAD * 1024 * 2);  // 41.4 MB
    carve(4096);                                                             // slack

    conv_feat<<<N_ATOMS, 256, 0, stream>>>(features, feat);
    pack_w<<<dim3(KP1 / 32, 4), 256, 0, stream>>>(W1, B1t, NFEAT, KP1);
    pack_w<<<dim3(8, 4), 256, 0, stream>>>(W2, B2t, 256, 256);
    pack_w<<<dim3(8, 4), 256, 0, stream>>>(W3, B3t, 256, 256);
    make_pw<<<(N_ATOMS + 255) / 256, 256, 0, stream>>>(W_comb, species, pw);
    zero_f<<<2, 256, 0, stream>>>(out, SS);

    // layer 1: [NPAD x 2880] * [2880 x 1024] -> h1 (pw-scaled silu), pipelined
    gemm1_pipe<<<158 * 8, 512, 0, stream>>>(feat, B1t, pw, h1);
    // layers 2+3+4 fused, block-local per 64-row x p slab
    mlp_tail<<<316 * 4, 256, 0, stream>>>(h1, B2t, B3t, W4, sidx, out);
}